// Round 5
// baseline (514.957 us; speedup 1.0000x reference)
//
#include <hip/hip_runtime.h>

#define N_NODES 50000
#define N_EDGES 1600000
#define IN_DIM 512
#define OUT_DIM 256

#define BM 64
#define BK 32
#define APAD 8                 // pad rows to 40 shorts = 80 B
#define LDA (BK + APAD)

typedef unsigned int u32;
typedef unsigned short u16;
typedef short bf16x8 __attribute__((ext_vector_type(8)));
typedef float f32x4 __attribute__((ext_vector_type(4)));

__device__ __forceinline__ float bf_lo(u32 u) { return __uint_as_float(u << 16); }
__device__ __forceinline__ float bf_hi(u32 u) { return __uint_as_float(u & 0xffff0000u); }
__device__ __forceinline__ u16 f_to_bf(float f) {
    u32 u = __float_as_uint(f);
    u32 r = (u + 0x7fffu + ((u >> 16) & 1u)) >> 16;   // RNE
    return (u16)r;
}

// ---------------------------------------------------------------------------
// prep: blocks [0,128) transpose+convert W -> WT bf16; blocks [128,324) zero cnt
// ---------------------------------------------------------------------------
__global__ __launch_bounds__(256) void prep(const float* __restrict__ W,
                                            u16* __restrict__ WT,
                                            int* __restrict__ cnt) {
    if (blockIdx.x < IN_DIM / 4) {
        const int n  = threadIdx.x;
        const int k0 = blockIdx.x * 4;
        ushort4 o;
        o.x = f_to_bf(W[(size_t)(k0 + 0) * OUT_DIM + n]);
        o.y = f_to_bf(W[(size_t)(k0 + 1) * OUT_DIM + n]);
        o.z = f_to_bf(W[(size_t)(k0 + 2) * OUT_DIM + n]);
        o.w = f_to_bf(W[(size_t)(k0 + 3) * OUT_DIM + n]);
        *(ushort4*)(WT + (size_t)n * IN_DIM + k0) = o;
    } else {
        const int i = (blockIdx.x - IN_DIM / 4) * 256 + threadIdx.x;
        if (i < N_NODES) cnt[i] = 0;
    }
}

// ---------------------------------------------------------------------------
// histogram of edge_row, 4 edges per thread
// ---------------------------------------------------------------------------
__global__ __launch_bounds__(256) void hist(const int* __restrict__ er,
                                            int* __restrict__ cnt) {
    const int i = blockIdx.x * blockDim.x + threadIdx.x;
    if (i >= N_EDGES / 4) return;
    const int4 e = ((const int4*)er)[i];
    atomicAdd(&cnt[e.x], 1);
    atomicAdd(&cnt[e.y], 1);
    atomicAdd(&cnt[e.z], 1);
    atomicAdd(&cnt[e.w], 1);
}

// pass 1: per-block exclusive scan; block totals to bsum
__global__ __launch_bounds__(256) void scan1(const int* __restrict__ cnt,
                                             int* __restrict__ row_ptr,
                                             int* __restrict__ bsum) {
    __shared__ int sh[256];
    const int t = threadIdx.x;
    const int i = blockIdx.x * 256 + t;
    const int v = (i < N_NODES) ? cnt[i] : 0;
    sh[t] = v;
    __syncthreads();
    #pragma unroll
    for (int off = 1; off < 256; off <<= 1) {
        const int tv = (t >= off) ? sh[t - off] : 0;
        __syncthreads();
        sh[t] += tv;
        __syncthreads();
    }
    if (i < N_NODES) row_ptr[i] = sh[t] - v;
    if (t == 255) bsum[blockIdx.x] = sh[255];
}

// pass 2: scan the block sums (single block)
__global__ __launch_bounds__(256) void scan2(int* __restrict__ bsum, int nb) {
    __shared__ int sh[256];
    const int t = threadIdx.x;
    const int v = (t < nb) ? bsum[t] : 0;
    sh[t] = v;
    __syncthreads();
    #pragma unroll
    for (int off = 1; off < 256; off <<= 1) {
        const int tv = (t >= off) ? sh[t - off] : 0;
        __syncthreads();
        sh[t] += tv;
        __syncthreads();
    }
    if (t < nb) bsum[t] = sh[t] - v;
}

// pass 3: add block prefix; produce row_ptr + cursor
__global__ __launch_bounds__(256) void scan3(int* __restrict__ row_ptr,
                                             const int* __restrict__ bsum,
                                             int* __restrict__ cursor) {
    const int t = threadIdx.x;
    const int i = blockIdx.x * 256 + t;
    if (i < N_NODES) {
        const int r = row_ptr[i] + bsum[blockIdx.x];
        row_ptr[i] = r;
        cursor[i]  = r;
    }
    if (blockIdx.x == 0 && t == 0) row_ptr[N_NODES] = N_EDGES;
}

// bucket edges into row-sorted order, 4 edges per thread
__global__ __launch_bounds__(256) void bucket(const int* __restrict__ er,
                                              const int* __restrict__ ec,
                                              const float* __restrict__ ev,
                                              int* __restrict__ cursor,
                                              int2* __restrict__ sedge) {
    const int i = blockIdx.x * blockDim.x + threadIdx.x;
    if (i >= N_EDGES / 4) return;
    const int4   r4 = ((const int4*)er)[i];
    const int4   c4 = ((const int4*)ec)[i];
    const float4 v4 = ((const float4*)ev)[i];
    int pos;
    pos = atomicAdd(&cursor[r4.x], 1); sedge[pos] = make_int2(c4.x, __float_as_int(v4.x));
    pos = atomicAdd(&cursor[r4.y], 1); sedge[pos] = make_int2(c4.y, __float_as_int(v4.y));
    pos = atomicAdd(&cursor[r4.z], 1); sedge[pos] = make_int2(c4.z, __float_as_int(v4.z));
    pos = atomicAdd(&cursor[r4.w], 1); sedge[pos] = make_int2(c4.w, __float_as_int(v4.w));
}

// ---------------------------------------------------------------------------
// GEMM: Sb[M,256] = bf16( X[M,512] @ W[512,256] ), MFMA 16x16x32 bf16
// block = 256 thr = 4 waves; tile 64x256; wave computes 64x64 (4x4 tiles)
// X read exactly once (BN = OUT_DIM); WT (256 KB) is L2-resident
// ---------------------------------------------------------------------------
__global__ __launch_bounds__(256) void gemm_mfma(const float* __restrict__ X,
                                                 const u16* __restrict__ WT,
                                                 u16* __restrict__ Sb) {
    __shared__ u16 As[BM * LDA];       // 5.1 KB
    __shared__ u16 Bs[OUT_DIM * LDA];  // 20.5 KB

    const int tid  = threadIdx.x;
    const int wave = tid >> 6;
    const int lane = tid & 63;
    const int r0   = blockIdx.x * BM;
    const int wn   = wave * 64;
    const int l15  = lane & 15;
    const int quad = lane >> 4;

    f32x4 acc[4][4];
    #pragma unroll
    for (int i = 0; i < 4; ++i)
        #pragma unroll
        for (int j = 0; j < 4; ++j) acc[i][j] = (f32x4)0.f;

    // A staging coords: row = tid>>2 (0..63), kq = (tid&3)*8
    const int arow = tid >> 2;
    const int akq  = (tid & 3) * 8;
    const int xrow = min(r0 + arow, N_NODES - 1);   // clamp; stores masked later
    const float* xsrc = X + (size_t)xrow * IN_DIM + akq;
    // B staging: thread stages WT row n = tid, 32 k per iter
    const u16* bsrc = WT + (size_t)tid * IN_DIM;

    for (int kc = 0; kc < IN_DIM; kc += BK) {
        {   // stage A: 8 fp32 -> 8 bf16 per thread
            const float4 f0 = *(const float4*)(xsrc + kc);
            const float4 f1 = *(const float4*)(xsrc + kc + 4);
            ushort4 p0, p1;
            p0.x = f_to_bf(f0.x); p0.y = f_to_bf(f0.y); p0.z = f_to_bf(f0.z); p0.w = f_to_bf(f0.w);
            p1.x = f_to_bf(f1.x); p1.y = f_to_bf(f1.y); p1.z = f_to_bf(f1.z); p1.w = f_to_bf(f1.w);
            *(ushort4*)&As[arow * LDA + akq + 0] = p0;
            *(ushort4*)&As[arow * LDA + akq + 4] = p1;
        }
        {   // stage B: 32 bf16 per thread
            const uint4 b0 = *(const uint4*)(bsrc + kc + 0);
            const uint4 b1 = *(const uint4*)(bsrc + kc + 8);
            const uint4 b2 = *(const uint4*)(bsrc + kc + 16);
            const uint4 b3 = *(const uint4*)(bsrc + kc + 24);
            *(uint4*)&Bs[tid * LDA + 0]  = b0;
            *(uint4*)&Bs[tid * LDA + 8]  = b1;
            *(uint4*)&Bs[tid * LDA + 16] = b2;
            *(uint4*)&Bs[tid * LDA + 24] = b3;
        }
        __syncthreads();

        bf16x8 af[4], bf[4];
        #pragma unroll
        for (int mt = 0; mt < 4; ++mt)
            af[mt] = *(const bf16x8*)&As[(mt * 16 + l15) * LDA + quad * 8];
        #pragma unroll
        for (int nt = 0; nt < 4; ++nt)
            bf[nt] = *(const bf16x8*)&Bs[(wn + nt * 16 + l15) * LDA + quad * 8];
        #pragma unroll
        for (int mt = 0; mt < 4; ++mt)
            #pragma unroll
            for (int nt = 0; nt < 4; ++nt)
                acc[mt][nt] = __builtin_amdgcn_mfma_f32_16x16x32_bf16(
                    af[mt], bf[nt], acc[mt][nt], 0, 0, 0);
        __syncthreads();
    }

    // epilogue: D[row = quad*4 + r][col = l15] per 16x16 tile
    #pragma unroll
    for (int mt = 0; mt < 4; ++mt) {
        #pragma unroll
        for (int r = 0; r < 4; ++r) {
            const int grow = r0 + mt * 16 + quad * 4 + r;
            if (grow < N_NODES) {
                u16* dst = Sb + (size_t)grow * OUT_DIM + wn + l15;
                #pragma unroll
                for (int nt = 0; nt < 4; ++nt)
                    dst[nt * 16] = f_to_bf(acc[mt][nt][r]);
            }
        }
    }
}

// ---------------------------------------------------------------------------
// out[r] = bias + sum_{e in row r} val[e] * Sb[col[e]]
// one wave per row; half-wave per edge stream (16B loads), 2 edges in flight;
// interleaved edge assignment, cross-half merge via shfl_xor at the end
// ---------------------------------------------------------------------------
__global__ __launch_bounds__(256) void csr_spmm(const int* __restrict__ row_ptr,
                                                const int2* __restrict__ sedge,
                                                const u16* __restrict__ Sb,
                                                const float* __restrict__ bias,
                                                float* __restrict__ out) {
    const int wave = threadIdx.x >> 6;
    const int lane = threadIdx.x & 63;
    const int hl   = lane & 31;        // channel group: 8 channels at hl*8
    const int half = lane >> 5;        // edge stream 0 / 1
    const int r = blockIdx.x * 4 + wave;
    if (r >= N_NODES) return;

    const int start = row_ptr[r];
    const int end   = row_ptr[r + 1];

    float acc[8];
    #pragma unroll
    for (int k = 0; k < 8; ++k) acc[k] = 0.f;

    for (int e0 = start; e0 < end; e0 += 64) {
        const int rem = end - e0;
        const int m = rem < 64 ? rem : 64;
        // lane holds edge e0 + 2*hl + half  (interleaved: half h, iter j -> 2j+h)
        int c = 0, vb = 0;
        const int my = 2 * hl + half;
        if (my < m) {
            const int2 t = sedge[e0 + my];
            c = t.x; vb = t.y;
        }
        const int jmax = (m + 1) >> 1;
        for (int j = 0; j < jmax; ++j) {
            const int src = j + (half << 5);          // lane holding edge 2j+half
            const int   cj = __shfl(c, src);
            const float vj = __uint_as_float((u32)__shfl(vb, src));
            const uint4 sv = *(const uint4*)(Sb + (size_t)cj * OUT_DIM + hl * 8);
            acc[0] += vj * bf_lo(sv.x); acc[1] += vj * bf_hi(sv.x);
            acc[2] += vj * bf_lo(sv.y); acc[3] += vj * bf_hi(sv.y);
            acc[4] += vj * bf_lo(sv.z); acc[5] += vj * bf_hi(sv.z);
            acc[6] += vj * bf_lo(sv.w); acc[7] += vj * bf_hi(sv.w);
        }
    }

    // merge the two half-wave partial sums
    #pragma unroll
    for (int k = 0; k < 8; ++k) acc[k] += __shfl_xor(acc[k], 32);

    if (half == 0) {
        const float4 b0 = *(const float4*)(bias + hl * 8);
        const float4 b1 = *(const float4*)(bias + hl * 8 + 4);
        float4 o0 = make_float4(acc[0] + b0.x, acc[1] + b0.y, acc[2] + b0.z, acc[3] + b0.w);
        float4 o1 = make_float4(acc[4] + b1.x, acc[5] + b1.y, acc[6] + b1.z, acc[7] + b1.w);
        float* dst = out + (size_t)r * OUT_DIM + hl * 8;
        *(float4*)(dst)     = o0;
        *(float4*)(dst + 4) = o1;
    }
}

extern "C" void kernel_launch(void* const* d_in, const int* in_sizes, int n_in,
                              void* d_out, int out_size, void* d_ws, size_t ws_size,
                              hipStream_t stream) {
    const float* X    = (const float*)d_in[0];
    const int*   er   = (const int*)d_in[1];
    const int*   ec   = (const int*)d_in[2];
    const float* ev   = (const float*)d_in[3];
    const float* W    = (const float*)d_in[4];
    const float* bias = (const float*)d_in[5];
    float* out        = (float*)d_out;

    // ws layout (~39.3 MB total)
    char* ws = (char*)d_ws;
    u16*  Sb      = (u16*) (ws);                       // 25,600,000 B
    u16*  WT      = (u16*) (ws + 25600000);            //    262,144 B
    int2* sedge   = (int2*)(ws + 25862144);            // 12,800,000 B
    int*  cnt     = (int*) (ws + 38662144);            //    200,000 B
    int*  row_ptr = (int*) (ws + 38862144);            //    200,004 B
    int*  cursor  = (int*) (ws + 39062160);            //    200,000 B
    int*  bsum    = (int*) (ws + 39262160);            //        784 B

    const int nb = (N_NODES + 255) / 256;              // 196

    hipLaunchKernelGGL(prep, dim3(IN_DIM / 4 + nb), dim3(256), 0, stream,
                       W, WT, cnt);
    hipLaunchKernelGGL(hist, dim3((N_EDGES / 4 + 255) / 256), dim3(256), 0, stream,
                       er, cnt);
    hipLaunchKernelGGL(scan1, dim3(nb), dim3(256), 0, stream, cnt, row_ptr, bsum);
    hipLaunchKernelGGL(scan2, dim3(1), dim3(256), 0, stream, bsum, nb);
    hipLaunchKernelGGL(scan3, dim3(nb), dim3(256), 0, stream, row_ptr, bsum, cursor);
    hipLaunchKernelGGL(bucket, dim3((N_EDGES / 4 + 255) / 256), dim3(256), 0, stream,
                       er, ec, ev, cursor, sedge);
    hipLaunchKernelGGL(gemm_mfma, dim3((N_NODES + BM - 1) / BM), dim3(256), 0, stream,
                       X, WT, Sb);
    hipLaunchKernelGGL(csr_spmm, dim3((N_NODES + 3) / 4), dim3(256), 0, stream,
                       row_ptr, sedge, Sb, bias, out);
}